// Round 1
// baseline (10809.621 us; speedup 1.0000x reference)
//
#include <hip/hip_runtime.h>
#include <hip/hip_bf16.h>

// Problem constants (from reference setup_inputs)
#define N_NODES 16384
#define FM      256
#define NF      (N_NODES * FM)          // 4,194,304 floats per branch tensor
#define NF4     (NF / 4)                // float4 count

// ---------------------------------------------------------------------------
// Degree / normalization prep
// ---------------------------------------------------------------------------

// dinv3 holds 3 * N_NODES floats (deg for f, s, g edge sets); init to 1.0
// (the self-loop weight). Also zero the 6 pooled-sum slots.
__global__ void deg_init_kernel(float* __restrict__ dinv3, float* __restrict__ pooled,
                                int n3) {
    int i = blockIdx.x * blockDim.x + threadIdx.x;
    if (i < n3) dinv3[i] = 1.0f;
    else if (i < n3 + 6) pooled[i - n3] = 0.0f;
}

__global__ void deg_edges_kernel(const int* __restrict__ dst,
                                 const float* __restrict__ ew,
                                 float* __restrict__ deg, int E) {
    int e = blockIdx.x * blockDim.x + threadIdx.x;
    if (e < E) atomicAdd(&deg[dst[e]], ew[e]);
}

__global__ void deg_finish_kernel(float* __restrict__ deg, int n3) {
    int i = blockIdx.x * blockDim.x + threadIdx.x;
    if (i < n3) deg[i] = rsqrtf(deg[i]);   // deg >= 1 always (self loop)
}

// ---------------------------------------------------------------------------
// fp32 GEMM: C[M,256] = A[M,256] @ B[256,256], all row-major.
// 64x64 tile, BK=16, 256 threads, 4x4 micro-tile per thread.
// ---------------------------------------------------------------------------
__global__ __launch_bounds__(256) void gemm256_kernel(const float* __restrict__ A,
                                                      const float* __restrict__ B,
                                                      float* __restrict__ C) {
    const int K = 256, N = 256;
    __shared__ float As[16][64];
    __shared__ float Bs[16][64];

    int tid = threadIdx.x;
    int tx = tid & 15;          // n-direction (x4)
    int ty = tid >> 4;          // m-direction (x4)
    int bm = blockIdx.x * 64;
    int bn = blockIdx.y * 64;

    float acc[4][4] = {};

    for (int k0 = 0; k0 < K; k0 += 16) {
        // A tile: 64 rows x 16 k. Each thread: one row, 4 consecutive k (float4).
        {
            int row = tid & 63;
            int kq = (tid >> 6) * 4;
            float4 a = *(const float4*)&A[(size_t)(bm + row) * K + k0 + kq];
            As[kq + 0][row] = a.x;
            As[kq + 1][row] = a.y;
            As[kq + 2][row] = a.z;
            As[kq + 3][row] = a.w;
            // B tile: 16 k x 64 n. Each thread: one k row, 4 consecutive n.
            int krow = tid >> 4;
            int nq = (tid & 15) * 4;
            *(float4*)&Bs[krow][nq] = *(const float4*)&B[(size_t)(k0 + krow) * N + bn + nq];
        }
        __syncthreads();
#pragma unroll
        for (int k = 0; k < 16; ++k) {
            float4 av = *(const float4*)&As[k][ty * 4];
            float4 bv = *(const float4*)&Bs[k][tx * 4];
            acc[0][0] += av.x * bv.x; acc[0][1] += av.x * bv.y;
            acc[0][2] += av.x * bv.z; acc[0][3] += av.x * bv.w;
            acc[1][0] += av.y * bv.x; acc[1][1] += av.y * bv.y;
            acc[1][2] += av.y * bv.z; acc[1][3] += av.y * bv.w;
            acc[2][0] += av.z * bv.x; acc[2][1] += av.z * bv.y;
            acc[2][2] += av.z * bv.z; acc[2][3] += av.z * bv.w;
            acc[3][0] += av.w * bv.x; acc[3][1] += av.w * bv.y;
            acc[3][2] += av.w * bv.z; acc[3][3] += av.w * bv.w;
        }
        __syncthreads();
    }
#pragma unroll
    for (int i = 0; i < 4; ++i) {
        float4 v = make_float4(acc[i][0], acc[i][1], acc[i][2], acc[i][3]);
        *(float4*)&C[(size_t)(bm + ty * 4 + i) * N + bn + tx * 4] = v;
    }
}

// ---------------------------------------------------------------------------
// GCN aggregation
// ---------------------------------------------------------------------------

// out[i][:] = h[i][:] * dinv[i]^2   (the self-loop term; also inits out)
__global__ void self_init_kernel(const float* __restrict__ h,
                                 const float* __restrict__ dinv,
                                 float* __restrict__ out, int total4) {
    int i = blockIdx.x * blockDim.x + threadIdx.x;
    if (i >= total4) return;
    int node = i >> 6;                     // FM/4 = 64 float4 per row
    float di = dinv[node];
    float nw = di * di;
    float4 v = ((const float4*)h)[i];
    v.x *= nw; v.y *= nw; v.z *= nw; v.w *= nw;
    ((float4*)out)[i] = v;
}

// One wave per edge; lane l handles float4 l of the 256-wide feature row.
__global__ __launch_bounds__(256) void aggregate_kernel(const float* __restrict__ h,
                                                        const int* __restrict__ src,
                                                        const int* __restrict__ dst,
                                                        const float* __restrict__ ew,
                                                        const float* __restrict__ dinv,
                                                        float* __restrict__ out, int E) {
    int gid = blockIdx.x * blockDim.x + threadIdx.x;
    int e = gid >> 6;
    if (e >= E) return;
    int lane = threadIdx.x & 63;
    int s = src[e], d = dst[e];
    float norm = dinv[s] * ew[e] * dinv[d];
    float4 v = ((const float4*)(h + (size_t)s * FM))[lane];
    float* o = out + (size_t)d * FM + lane * 4;
    atomicAdd(o + 0, v.x * norm);
    atomicAdd(o + 1, v.y * norm);
    atomicAdd(o + 2, v.z * norm);
    atomicAdd(o + 3, v.w * norm);
}

// x = relu(x + b), b broadcast along rows
__global__ void bias_relu_kernel(float* __restrict__ x, const float* __restrict__ b,
                                 int total4) {
    int i = blockIdx.x * blockDim.x + threadIdx.x;
    if (i >= total4) return;
    float4 v = ((float4*)x)[i];
    float4 bb = *(const float4*)(b + (i & 63) * 4);
    v.x = fmaxf(v.x + bb.x, 0.0f);
    v.y = fmaxf(v.y + bb.y, 0.0f);
    v.z = fmaxf(v.z + bb.z, 0.0f);
    v.w = fmaxf(v.w + bb.w, 0.0f);
    ((float4*)x)[i] = v;
}

// ---------------------------------------------------------------------------
// SE attention
// ---------------------------------------------------------------------------

// Sum-reduce each branch tensor (grid.y = branch c, 256 blocks per branch).
__global__ __launch_bounds__(256) void reduce_branch_kernel(const float* __restrict__ br,
                                                            float* __restrict__ pooled) {
    int c = blockIdx.y;
    const float4* p = (const float4*)(br + (size_t)c * NF + (size_t)blockIdx.x * 16384);
    float s = 0.0f;
#pragma unroll
    for (int i = 0; i < 16; ++i) {
        float4 v = p[threadIdx.x + i * 256];
        s += v.x + v.y + v.z + v.w;
    }
    for (int o = 32; o > 0; o >>= 1) s += __shfl_down(s, o);
    __shared__ float wsum[4];
    if ((threadIdx.x & 63) == 0) wsum[threadIdx.x >> 6] = s;
    __syncthreads();
    if (threadIdx.x == 0)
        atomicAdd(&pooled[c], wsum[0] + wsum[1] + wsum[2] + wsum[3]);
}

__global__ void se_kernel(const float* __restrict__ pooled_sum,
                          const float* __restrict__ fc1_w, const float* __restrict__ fc1_b,
                          const float* __restrict__ fc2_w, const float* __restrict__ fc2_b,
                          float* __restrict__ att) {
    __shared__ float p[6];
    __shared__ float hbuf[30];
    int t = threadIdx.x;
    if (t < 6) p[t] = pooled_sum[t] * (1.0f / ((float)N_NODES * (float)FM));
    __syncthreads();
    if (t < 30) {
        float a = fc1_b[t];
#pragma unroll
        for (int c = 0; c < 6; ++c) a += fc1_w[t * 6 + c] * p[c];
        hbuf[t] = fmaxf(a, 0.0f);
    }
    __syncthreads();
    if (t < 6) {
        float a = fc2_b[t];
#pragma unroll
        for (int j = 0; j < 30; ++j) a += fc2_w[t * 30 + j] * hbuf[j];
        att[t] = 1.0f / (1.0f + expf(-a));
    }
}

// out[n][f] = sum_c cnn_w[c] * relu(att[c] * br_c[n][f]) + cnn_b
__global__ void combine_kernel(const float* __restrict__ br,
                               const float* __restrict__ att,
                               const float* __restrict__ cnn_w,
                               const float* __restrict__ cnn_b,
                               float* __restrict__ out, int total4) {
    int i = blockIdx.x * blockDim.x + threadIdx.x;
    if (i >= total4) return;
    float a[6], w[6];
#pragma unroll
    for (int c = 0; c < 6; ++c) { a[c] = att[c]; w[c] = cnn_w[c]; }
    float cb = cnn_b[0];
    float4 acc = make_float4(cb, cb, cb, cb);
#pragma unroll
    for (int c = 0; c < 6; ++c) {
        float4 v = ((const float4*)(br + (size_t)c * NF))[i];
        acc.x += w[c] * fmaxf(a[c] * v.x, 0.0f);
        acc.y += w[c] * fmaxf(a[c] * v.y, 0.0f);
        acc.z += w[c] * fmaxf(a[c] * v.z, 0.0f);
        acc.w += w[c] * fmaxf(a[c] * v.w, 0.0f);
    }
    ((float4*)out)[i] = acc;
}

// ---------------------------------------------------------------------------
// Host orchestration
// ---------------------------------------------------------------------------

static void run_conv(const float* in, const float* W, const float* b,
                     const int* edges, const float* ew, const float* dinv,
                     float* h_scratch, float* out, int E, hipStream_t stream) {
    dim3 ggrid(N_NODES / 64, FM / 64);
    gemm256_kernel<<<ggrid, 256, 0, stream>>>(in, W, h_scratch);
    self_init_kernel<<<NF4 / 256, 256, 0, stream>>>(h_scratch, dinv, out, NF4);
    int aggBlocks = (E * 64) / 256;
    aggregate_kernel<<<aggBlocks, 256, 0, stream>>>(h_scratch, edges, edges + E,
                                                    ew, dinv, out, E);
    bias_relu_kernel<<<NF4 / 256, 256, 0, stream>>>(out, b, NF4);
}

extern "C" void kernel_launch(void* const* d_in, const int* in_sizes, int n_in,
                              void* d_out, int out_size, void* d_ws, size_t ws_size,
                              hipStream_t stream) {
    const float* x      = (const float*)d_in[0];
    const int*   ed_f   = (const int*)d_in[1];
    const float* ew_f   = (const float*)d_in[2];
    const int*   ed_s   = (const int*)d_in[3];
    const float* ew_s   = (const float*)d_in[4];
    const int*   ed_g   = (const int*)d_in[5];
    const float* ew_g   = (const float*)d_in[6];
    const float* Wf1 = (const float*)d_in[7];  const float* bf1 = (const float*)d_in[8];
    const float* Wf2 = (const float*)d_in[9];  const float* bf2 = (const float*)d_in[10];
    const float* Ws1 = (const float*)d_in[11]; const float* bs1 = (const float*)d_in[12];
    const float* Ws2 = (const float*)d_in[13]; const float* bs2 = (const float*)d_in[14];
    const float* Wg1 = (const float*)d_in[15]; const float* bg1 = (const float*)d_in[16];
    const float* Wg2 = (const float*)d_in[17]; const float* bg2 = (const float*)d_in[18];
    const float* fc1_w = (const float*)d_in[19]; const float* fc1_b = (const float*)d_in[20];
    const float* fc2_w = (const float*)d_in[21]; const float* fc2_b = (const float*)d_in[22];
    const float* cnn_w = (const float*)d_in[23]; const float* cnn_b = (const float*)d_in[24];

    const int E = in_sizes[1] / 2;   // 524288

    // Workspace layout (floats):
    //   [0, 6*NF)              : 6 branch outputs f1,f2,s1,s2,g1,g2 (contiguous)
    //   [6*NF, 6*NF+3*NN)      : dinv for f,s,g edge sets
    //   [.., +6)               : pooled sums
    //   [.., +6)               : att
    float* ws   = (float*)d_ws;
    float* br   = ws;                              // 6 * NF
    float* dinv3 = ws + (size_t)6 * NF;            // 3 * N_NODES
    float* pooled = dinv3 + 3 * N_NODES;           // 6
    float* att    = pooled + 6;                    // 6
    float* dinv_f = dinv3;
    float* dinv_s = dinv3 + N_NODES;
    float* dinv_g = dinv3 + 2 * N_NODES;

    float* f1 = br + (size_t)0 * NF;
    float* f2 = br + (size_t)1 * NF;
    float* s1 = br + (size_t)2 * NF;
    float* s2 = br + (size_t)3 * NF;
    float* g1 = br + (size_t)4 * NF;
    float* g2 = br + (size_t)5 * NF;

    float* h = (float*)d_out;                      // GEMM scratch; overwritten at end

    // --- degree / dinv prep for the 3 edge sets ---
    int n3 = 3 * N_NODES;
    deg_init_kernel<<<(n3 + 6 + 255) / 256, 256, 0, stream>>>(dinv3, pooled, n3);
    deg_edges_kernel<<<(E + 255) / 256, 256, 0, stream>>>(ed_f + E, ew_f, dinv_f, E);
    deg_edges_kernel<<<(E + 255) / 256, 256, 0, stream>>>(ed_s + E, ew_s, dinv_s, E);
    deg_edges_kernel<<<(E + 255) / 256, 256, 0, stream>>>(ed_g + E, ew_g, dinv_g, E);
    deg_finish_kernel<<<(n3 + 255) / 256, 256, 0, stream>>>(dinv3, n3);

    // --- six GCN convs ---
    run_conv(x,  Wf1, bf1, ed_f, ew_f, dinv_f, h, f1, E, stream);
    run_conv(f1, Wf2, bf2, ed_f, ew_f, dinv_f, h, f2, E, stream);
    run_conv(x,  Ws1, bs1, ed_s, ew_s, dinv_s, h, s1, E, stream);
    run_conv(s1, Ws2, bs2, ed_s, ew_s, dinv_s, h, s2, E, stream);
    run_conv(x,  Wg1, bg1, ed_g, ew_g, dinv_g, h, g1, E, stream);
    run_conv(g1, Wg2, bg2, ed_g, ew_g, dinv_g, h, g2, E, stream);

    // --- SE attention ---
    dim3 rgrid(256, 6);
    reduce_branch_kernel<<<rgrid, 256, 0, stream>>>(br, pooled);
    se_kernel<<<1, 64, 0, stream>>>(pooled, fc1_w, fc1_b, fc2_w, fc2_b, att);

    // --- final 1x1 conv combine ---
    combine_kernel<<<NF4 / 256, 256, 0, stream>>>(br, att, cnn_w, cnn_b,
                                                  (float*)d_out, NF4);
}

// Round 5
// 905.892 us; speedup vs baseline: 11.9326x; 11.9326x over previous
//
#include <hip/hip_runtime.h>
#include <hip/hip_bf16.h>

// Problem constants (from reference setup_inputs)
#define N_NODES 16384
#define FM      256
#define NF      (N_NODES * FM)          // 4,194,304 floats per branch tensor
#define NF4     (NF / 4)                // float4 count

// ---------------------------------------------------------------------------
// Init: dinv3 = 1.0 (self-loop weight), edge-count histograms = 0, pooled = 0
// ---------------------------------------------------------------------------
__global__ void init_kernel(float* __restrict__ dinv3, int* __restrict__ cnt3,
                            float* __restrict__ pooled) {
    int i = blockIdx.x * blockDim.x + threadIdx.x;
    int n3 = 3 * N_NODES;
    if (i < n3) {
        dinv3[i] = 1.0f;
        cnt3[i] = 0;
    } else if (i < n3 + 6) {
        pooled[i - n3] = 0.0f;
    }
}

__global__ void deg_edges_kernel(const int* __restrict__ dst,
                                 const float* __restrict__ ew,
                                 float* __restrict__ deg,
                                 int* __restrict__ cnt, int E) {
    int e = blockIdx.x * blockDim.x + threadIdx.x;
    if (e < E) {
        int d = dst[e];
        atomicAdd(&deg[d], ew[e]);
        atomicAdd(&cnt[d], 1);
    }
}

__global__ void deg_finish_kernel(float* __restrict__ deg, int n3) {
    int i = blockIdx.x * blockDim.x + threadIdx.x;
    if (i < n3) deg[i] = rsqrtf(deg[i]);   // deg >= 1 always (self loop)
}

// ---------------------------------------------------------------------------
// Exclusive prefix sum of 16384 counts -> row_start[16385], cursor[16384]
// Single block of 1024 threads, 16 elements per thread.
// ---------------------------------------------------------------------------
__global__ __launch_bounds__(1024) void scan_kernel(const int* __restrict__ cnt,
                                                    int* __restrict__ row_start,
                                                    int* __restrict__ cursor) {
    __shared__ int part[1024];
    int t = threadIdx.x;
    int base = t * 16;
    int local[16];
    int s = 0;
#pragma unroll
    for (int i = 0; i < 16; ++i) { local[i] = cnt[base + i]; s += local[i]; }
    part[t] = s;
    __syncthreads();
    for (int off = 1; off < 1024; off <<= 1) {
        int v = (t >= off) ? part[t - off] : 0;
        __syncthreads();
        part[t] += v;
        __syncthreads();
    }
    int pre = (t > 0) ? part[t - 1] : 0;
#pragma unroll
    for (int i = 0; i < 16; ++i) {
        row_start[base + i] = pre;
        cursor[base + i] = pre;
        pre += local[i];
    }
    if (t == 1023) row_start[N_NODES] = pre;
}

// Scatter edges into CSR slots; precompute norm = dinv[s]*w*dinv[d].
__global__ void scatter_kernel(const int* __restrict__ src,
                               const int* __restrict__ dst,
                               const float* __restrict__ ew,
                               const float* __restrict__ dinv,
                               int* __restrict__ cursor,
                               int* __restrict__ csr_src,
                               float* __restrict__ csr_norm, int E) {
    int e = blockIdx.x * blockDim.x + threadIdx.x;
    if (e >= E) return;
    int s = src[e], d = dst[e];
    int pos = atomicAdd(&cursor[d], 1);
    csr_src[pos] = s;
    csr_norm[pos] = dinv[s] * ew[e] * dinv[d];
}

// ---------------------------------------------------------------------------
// fp32 GEMM: C[M,256] = A[M,256] @ B[256,256], all row-major.
// 64x64 tile, BK=16, 256 threads, 4x4 micro-tile per thread.
// ---------------------------------------------------------------------------
__global__ __launch_bounds__(256) void gemm256_kernel(const float* __restrict__ A,
                                                      const float* __restrict__ B,
                                                      float* __restrict__ C) {
    const int K = 256, N = 256;
    __shared__ float As[16][64];
    __shared__ float Bs[16][64];

    int tid = threadIdx.x;
    int tx = tid & 15;          // n-direction (x4)
    int ty = tid >> 4;          // m-direction (x4)
    int bm = blockIdx.x * 64;
    int bn = blockIdx.y * 64;

    float acc[4][4] = {};

    for (int k0 = 0; k0 < K; k0 += 16) {
        {
            int row = tid & 63;
            int kq = (tid >> 6) * 4;
            float4 a = *(const float4*)&A[(size_t)(bm + row) * K + k0 + kq];
            As[kq + 0][row] = a.x;
            As[kq + 1][row] = a.y;
            As[kq + 2][row] = a.z;
            As[kq + 3][row] = a.w;
            int krow = tid >> 4;
            int nq = (tid & 15) * 4;
            *(float4*)&Bs[krow][nq] = *(const float4*)&B[(size_t)(k0 + krow) * N + bn + nq];
        }
        __syncthreads();
#pragma unroll
        for (int k = 0; k < 16; ++k) {
            float4 av = *(const float4*)&As[k][ty * 4];
            float4 bv = *(const float4*)&Bs[k][tx * 4];
            acc[0][0] += av.x * bv.x; acc[0][1] += av.x * bv.y;
            acc[0][2] += av.x * bv.z; acc[0][3] += av.x * bv.w;
            acc[1][0] += av.y * bv.x; acc[1][1] += av.y * bv.y;
            acc[1][2] += av.y * bv.z; acc[1][3] += av.y * bv.w;
            acc[2][0] += av.z * bv.x; acc[2][1] += av.z * bv.y;
            acc[2][2] += av.z * bv.z; acc[2][3] += av.z * bv.w;
            acc[3][0] += av.w * bv.x; acc[3][1] += av.w * bv.y;
            acc[3][2] += av.w * bv.z; acc[3][3] += av.w * bv.w;
        }
        __syncthreads();
    }
#pragma unroll
    for (int i = 0; i < 4; ++i) {
        float4 v = make_float4(acc[i][0], acc[i][1], acc[i][2], acc[i][3]);
        *(float4*)&C[(size_t)(bm + ty * 4 + i) * N + bn + tx * 4] = v;
    }
}

// ---------------------------------------------------------------------------
// Fused GCN aggregation (CSR, gather-by-destination):
// out[d][:] = relu( b + dinv[d]^2 * h[d][:] + sum_j norm_j * h[src_j][:] )
// One wave per node; lane l owns float4 l of the 256-wide feature row.
// ---------------------------------------------------------------------------
__global__ __launch_bounds__(256) void gcn_aggregate_csr(const float* __restrict__ h,
                                                         const int* __restrict__ row_start,
                                                         const int* __restrict__ csr_src,
                                                         const float* __restrict__ csr_norm,
                                                         const float* __restrict__ dinv,
                                                         const float* __restrict__ bias,
                                                         float* __restrict__ out) {
    int node = blockIdx.x * 4 + (threadIdx.x >> 6);
    int lane = threadIdx.x & 63;
    const float4* hp = (const float4*)h;

    float di = dinv[node];
    float sw = di * di;
    float4 v = hp[(size_t)node * 64 + lane];
    float4 acc = make_float4(v.x * sw, v.y * sw, v.z * sw, v.w * sw);

    int beg = row_start[node];
    int end = row_start[node + 1];
    int j = beg;
    for (; j + 1 < end; j += 2) {
        int s0 = csr_src[j];
        int s1 = csr_src[j + 1];
        float w0 = csr_norm[j];
        float w1 = csr_norm[j + 1];
        float4 v0 = hp[(size_t)s0 * 64 + lane];
        float4 v1 = hp[(size_t)s1 * 64 + lane];
        acc.x += w0 * v0.x + w1 * v1.x;
        acc.y += w0 * v0.y + w1 * v1.y;
        acc.z += w0 * v0.z + w1 * v1.z;
        acc.w += w0 * v0.w + w1 * v1.w;
    }
    if (j < end) {
        int s0 = csr_src[j];
        float w0 = csr_norm[j];
        float4 v0 = hp[(size_t)s0 * 64 + lane];
        acc.x += w0 * v0.x;
        acc.y += w0 * v0.y;
        acc.z += w0 * v0.z;
        acc.w += w0 * v0.w;
    }
    float4 bb = ((const float4*)bias)[lane];
    acc.x = fmaxf(acc.x + bb.x, 0.0f);
    acc.y = fmaxf(acc.y + bb.y, 0.0f);
    acc.z = fmaxf(acc.z + bb.z, 0.0f);
    acc.w = fmaxf(acc.w + bb.w, 0.0f);
    ((float4*)out)[(size_t)node * 64 + lane] = acc;
}

// ---------------------------------------------------------------------------
// SE attention
// ---------------------------------------------------------------------------
__global__ __launch_bounds__(256) void reduce_branch_kernel(const float* __restrict__ br,
                                                            float* __restrict__ pooled) {
    int c = blockIdx.y;
    const float4* p = (const float4*)(br + (size_t)c * NF + (size_t)blockIdx.x * 16384);
    float s = 0.0f;
#pragma unroll
    for (int i = 0; i < 16; ++i) {
        float4 v = p[threadIdx.x + i * 256];
        s += v.x + v.y + v.z + v.w;
    }
    for (int o = 32; o > 0; o >>= 1) s += __shfl_down(s, o);
    __shared__ float wsum[4];
    if ((threadIdx.x & 63) == 0) wsum[threadIdx.x >> 6] = s;
    __syncthreads();
    if (threadIdx.x == 0)
        atomicAdd(&pooled[c], wsum[0] + wsum[1] + wsum[2] + wsum[3]);
}

__global__ void se_kernel(const float* __restrict__ pooled_sum,
                          const float* __restrict__ fc1_w, const float* __restrict__ fc1_b,
                          const float* __restrict__ fc2_w, const float* __restrict__ fc2_b,
                          float* __restrict__ att) {
    __shared__ float p[6];
    __shared__ float hbuf[30];
    int t = threadIdx.x;
    if (t < 6) p[t] = pooled_sum[t] * (1.0f / ((float)N_NODES * (float)FM));
    __syncthreads();
    if (t < 30) {
        float a = fc1_b[t];
#pragma unroll
        for (int c = 0; c < 6; ++c) a += fc1_w[t * 6 + c] * p[c];
        hbuf[t] = fmaxf(a, 0.0f);
    }
    __syncthreads();
    if (t < 6) {
        float a = fc2_b[t];
#pragma unroll
        for (int j = 0; j < 30; ++j) a += fc2_w[t * 30 + j] * hbuf[j];
        att[t] = 1.0f / (1.0f + expf(-a));
    }
}

// out[n][f] = sum_c cnn_w[c] * relu(att[c] * br_c[n][f]) + cnn_b
__global__ void combine_kernel(const float* __restrict__ br,
                               const float* __restrict__ att,
                               const float* __restrict__ cnn_w,
                               const float* __restrict__ cnn_b,
                               float* __restrict__ out, int total4) {
    int i = blockIdx.x * blockDim.x + threadIdx.x;
    if (i >= total4) return;
    float a[6], w[6];
#pragma unroll
    for (int c = 0; c < 6; ++c) { a[c] = att[c]; w[c] = cnn_w[c]; }
    float cb = cnn_b[0];
    float4 acc = make_float4(cb, cb, cb, cb);
#pragma unroll
    for (int c = 0; c < 6; ++c) {
        float4 v = ((const float4*)(br + (size_t)c * NF))[i];
        acc.x += w[c] * fmaxf(a[c] * v.x, 0.0f);
        acc.y += w[c] * fmaxf(a[c] * v.y, 0.0f);
        acc.z += w[c] * fmaxf(a[c] * v.z, 0.0f);
        acc.w += w[c] * fmaxf(a[c] * v.w, 0.0f);
    }
    ((float4*)out)[i] = acc;
}

// ---------------------------------------------------------------------------
// Host orchestration
// ---------------------------------------------------------------------------

static void run_conv(const float* in, const float* W, const float* b,
                     const int* row_start, const int* csr_src, const float* csr_norm,
                     const float* dinv, float* h_scratch, float* out,
                     hipStream_t stream) {
    dim3 ggrid(N_NODES / 64, FM / 64);
    gemm256_kernel<<<ggrid, 256, 0, stream>>>(in, W, h_scratch);
    gcn_aggregate_csr<<<N_NODES / 4, 256, 0, stream>>>(h_scratch, row_start, csr_src,
                                                       csr_norm, dinv, b, out);
}

extern "C" void kernel_launch(void* const* d_in, const int* in_sizes, int n_in,
                              void* d_out, int out_size, void* d_ws, size_t ws_size,
                              hipStream_t stream) {
    const float* x      = (const float*)d_in[0];
    const int*   ed_f   = (const int*)d_in[1];
    const float* ew_f   = (const float*)d_in[2];
    const int*   ed_s   = (const int*)d_in[3];
    const float* ew_s   = (const float*)d_in[4];
    const int*   ed_g   = (const int*)d_in[5];
    const float* ew_g   = (const float*)d_in[6];
    const float* Wf1 = (const float*)d_in[7];  const float* bf1 = (const float*)d_in[8];
    const float* Wf2 = (const float*)d_in[9];  const float* bf2 = (const float*)d_in[10];
    const float* Ws1 = (const float*)d_in[11]; const float* bs1 = (const float*)d_in[12];
    const float* Ws2 = (const float*)d_in[13]; const float* bs2 = (const float*)d_in[14];
    const float* Wg1 = (const float*)d_in[15]; const float* bg1 = (const float*)d_in[16];
    const float* Wg2 = (const float*)d_in[17]; const float* bg2 = (const float*)d_in[18];
    const float* fc1_w = (const float*)d_in[19]; const float* fc1_b = (const float*)d_in[20];
    const float* fc2_w = (const float*)d_in[21]; const float* fc2_b = (const float*)d_in[22];
    const float* cnn_w = (const float*)d_in[23]; const float* cnn_b = (const float*)d_in[24];

    const int E = in_sizes[1] / 2;   // 524288

    // Workspace layout (floats/ints, 4B elements):
    float* ws = (float*)d_ws;
    float* br = ws;                                    // 6 * NF floats
    float* dinv3  = ws + (size_t)6 * NF;               // 3 * N_NODES
    float* pooled = dinv3 + 3 * N_NODES;               // 6
    float* att    = pooled + 6;                        // 6 (+4 pad)
    int*   cnt3      = (int*)(att + 10);               // 3 * N_NODES
    int*   cursor3   = cnt3 + 3 * N_NODES;             // 3 * N_NODES
    int*   rowstart3 = cursor3 + 3 * N_NODES;          // 3 * (N_NODES+1) (+pad)
    int*   csr_src3  = rowstart3 + 3 * (N_NODES + 2);  // 3 * E
    float* csr_norm3 = (float*)(csr_src3 + (size_t)3 * E);  // 3 * E

    float* dinv_set[3]   = { dinv3, dinv3 + N_NODES, dinv3 + 2 * N_NODES };
    int*   cnt_set[3]    = { cnt3, cnt3 + N_NODES, cnt3 + 2 * N_NODES };
    int*   cursor_set[3] = { cursor3, cursor3 + N_NODES, cursor3 + 2 * N_NODES };
    int*   rs_set[3]     = { rowstart3, rowstart3 + (N_NODES + 2),
                             rowstart3 + 2 * (N_NODES + 2) };
    int*   csrc_set[3]   = { csr_src3, csr_src3 + E, csr_src3 + 2 * E };
    float* cnorm_set[3]  = { csr_norm3, csr_norm3 + E, csr_norm3 + 2 * E };
    const int*   ed_set[3] = { ed_f, ed_s, ed_g };
    const float* ew_set[3] = { ew_f, ew_s, ew_g };

    float* f1 = br + (size_t)0 * NF;
    float* f2 = br + (size_t)1 * NF;
    float* s1 = br + (size_t)2 * NF;
    float* s2 = br + (size_t)3 * NF;
    float* g1 = br + (size_t)4 * NF;
    float* g2 = br + (size_t)5 * NF;

    float* h = (float*)d_out;     // GEMM scratch; fully overwritten by combine

    // --- init + degree + CSR build for the 3 edge sets ---
    int n3 = 3 * N_NODES;
    init_kernel<<<(n3 + 6 + 255) / 256, 256, 0, stream>>>(dinv3, cnt3, pooled);
    for (int t = 0; t < 3; ++t)
        deg_edges_kernel<<<(E + 255) / 256, 256, 0, stream>>>(ed_set[t] + E, ew_set[t],
                                                              dinv_set[t], cnt_set[t], E);
    deg_finish_kernel<<<(n3 + 255) / 256, 256, 0, stream>>>(dinv3, n3);
    for (int t = 0; t < 3; ++t) {
        scan_kernel<<<1, 1024, 0, stream>>>(cnt_set[t], rs_set[t], cursor_set[t]);
        scatter_kernel<<<(E + 255) / 256, 256, 0, stream>>>(ed_set[t], ed_set[t] + E,
                                                            ew_set[t], dinv_set[t],
                                                            cursor_set[t], csrc_set[t],
                                                            cnorm_set[t], E);
    }

    // --- six GCN convs ---
    run_conv(x,  Wf1, bf1, rs_set[0], csrc_set[0], cnorm_set[0], dinv_set[0], h, f1, stream);
    run_conv(f1, Wf2, bf2, rs_set[0], csrc_set[0], cnorm_set[0], dinv_set[0], h, f2, stream);
    run_conv(x,  Ws1, bs1, rs_set[1], csrc_set[1], cnorm_set[1], dinv_set[1], h, s1, stream);
    run_conv(s1, Ws2, bs2, rs_set[1], csrc_set[1], cnorm_set[1], dinv_set[1], h, s2, stream);
    run_conv(x,  Wg1, bg1, rs_set[2], csrc_set[2], cnorm_set[2], dinv_set[2], h, g1, stream);
    run_conv(g1, Wg2, bg2, rs_set[2], csrc_set[2], cnorm_set[2], dinv_set[2], h, g2, stream);

    // --- SE attention ---
    dim3 rgrid(256, 6);
    reduce_branch_kernel<<<rgrid, 256, 0, stream>>>(br, pooled);
    se_kernel<<<1, 64, 0, stream>>>(pooled, fc1_w, fc1_b, fc2_w, fc2_b, att);

    // --- final 1x1 conv combine ---
    combine_kernel<<<NF4 / 256, 256, 0, stream>>>(br, att, cnn_w, cnn_b,
                                                  (float*)d_out, NF4);
}